// Round 6
// baseline (127.518 us; speedup 1.0000x reference)
//
#include <hip/hip_runtime.h>
#include <hip/hip_bf16.h>

#define KW   7
#define PADW 3
#define HW   56
#define PH   62          // padded plane height/width (56 + 6)
#define LDW  64          // LDS row stride (floats)
#define NTHREADS 448     // 56 cols * 8 row-groups; 7 px/thread vertical strip
#define PPT  7           // pixels per thread (vertical)

#define LOG2E 1.44269504088896340736f

__global__ __launch_bounds__(NTHREADS) void saconv_kernel(
    const float* __restrict__ x,
    const float* __restrict__ r,
    const float* __restrict__ Wq,
    const float* __restrict__ Wk,
    const float* __restrict__ Wv,
    const float* __restrict__ Wr,
    const float* __restrict__ up,
    const float* __restrict__ vp,
    float* __restrict__ out)
{
    __shared__ float xs[PH][LDW];   // full padded plane of one (b,g): 15.9 KB
    __shared__ float ro[KW * KW];

    const int tid = threadIdx.x;
    const int bid = blockIdx.x;     // 256 blocks = B * G, one plane per block
    const int g   = bid & 63;
    const int b   = bid >> 6;

    // per-group scalars (wave-uniform -> scalar loads)
    const float wq = Wq[g];
    const float wk = Wk[g];
    const float wv = Wv[g];
    const float ug = up[g];
    const float vg = vp[g];

    // ro[pos] = sum_c r[(g*4+c), pos] * Wr[g*4+c]   (pos = i*7+j, row-major)
    if (tid < KW * KW) {
        float acc = 0.f;
#pragma unroll
        for (int c = 0; c < 4; ++c)
            acc += r[(g * 4 + c) * (KW * KW) + tid] * Wr[g * 4 + c];
        ro[tid] = acc;
    }

    // stage the whole padded plane (zeros in the 3-wide halo + stride pad)
    const float* xb = x + (size_t)(b * 64 + g) * (HW * HW);
    for (int idx = tid; idx < PH * LDW; idx += NTHREADS) {
        const int ty = idx >> 6;          // 0..61
        const int tx = idx & 63;          // 0..63
        const int gy = ty - PADW;
        const int gx = tx - PADW;
        float v = 0.f;
        if (gy >= 0 && gy < HW && gx >= 0 && gx < HW)
            v = xb[gy * HW + gx];
        xs[ty][tx] = v;
    }
    __syncthreads();

    const int col  = tid % HW;            // 0..55
    const int rg   = tid / HW;            // 0..7
    const int row0 = rg * PPT;            // first pixel row of this thread

    // preload ro into registers: each entry is reused by all 7 pixels
    float rr[KW * KW];
#pragma unroll
    for (int k = 0; k < KW * KW; ++k) rr[k] = ro[k];

    // per-pixel constants (exp -> exp2, log2e folded in)
    float a2[PPT], cc2[PPT];
#pragma unroll
    for (int p = 0; p < PPT; ++p) {
        const float xc = xs[row0 + p + PADW][col + PADW];
        const float q  = xc * wq;
        a2[p]  = (q + ug) * wk * LOG2E;
        cc2[p] = (q + vg) * LOG2E;
    }

    float se[PPT], sx[PPT];
#pragma unroll
    for (int p = 0; p < PPT; ++p) { se[p] = 0.f; sx[p] = 0.f; }

    // March over the 13 window rows shared by this thread's 7 pixels.
    // Row slice (7 floats) is read once from LDS and reused by every pixel
    // whose 7x7 window covers it. Padding taps stay in the softmax (xv=0
    // there but the ro bias term remains -- matches the reference).
#pragma unroll
    for (int R = 0; R < PPT + KW - 1; ++R) {   // 13
        float xr[KW];
#pragma unroll
        for (int j = 0; j < KW; ++j)
            xr[j] = xs[row0 + R][col + j];
#pragma unroll
        for (int p = 0; p < PPT; ++p) {
            const int i = R - p;               // tap row for pixel p (compile-time)
            if (i >= 0 && i < KW) {
#pragma unroll
                for (int j = 0; j < KW; ++j) {
                    const float l2 = __builtin_fmaf(a2[p], xr[j],
                                                    cc2[p] * rr[i * KW + j]);
                    const float e  = __builtin_amdgcn_exp2f(l2);  // v_exp_f32
                    se[p] += e;
                    sx[p] = __builtin_fmaf(e, xr[j], sx[p]);
                }
            }
        }
    }

    const size_t base = (size_t)(b * 64 + g) * (HW * HW);
#pragma unroll
    for (int p = 0; p < PPT; ++p) {
        out[base + (row0 + p) * HW + col] =
            wv * sx[p] * __builtin_amdgcn_rcpf(se[p]);
    }
}

extern "C" void kernel_launch(void* const* d_in, const int* in_sizes, int n_in,
                              void* d_out, int out_size, void* d_ws, size_t ws_size,
                              hipStream_t stream) {
    const float* x  = (const float*)d_in[0];
    const float* r  = (const float*)d_in[1];
    const float* Wq = (const float*)d_in[2];
    const float* Wk = (const float*)d_in[3];
    const float* Wv = (const float*)d_in[4];
    const float* Wr = (const float*)d_in[5];
    const float* up = (const float*)d_in[6];
    const float* vp = (const float*)d_in[7];
    float* out = (float*)d_out;

    const int grid = 4 * 64;   // one (b,g) plane per block, 256 = #CUs
    saconv_kernel<<<grid, NTHREADS, 0, stream>>>(x, r, Wq, Wk, Wv, Wr, up, vp, out);
}

// Round 7
// 80.361 us; speedup vs baseline: 1.5868x; 1.5868x over previous
//
#include <hip/hip_runtime.h>

#define KW     7
#define PADW   3
#define HW     56
#define CHROWS 14               // pixel rows per block
#define TILE_H 20               // 14 + 6 halo
#define TILE_W 64               // 62 used
#define NTHREADS 448            // 7 waves; lane = col (56 active), tid>>6 = row-group
#define NCHUNK 4                // 56 / 14
#define PPT    2                // pixels per thread (vertical pair)

#define LOG2E 1.44269504088896340736f

__global__ __launch_bounds__(NTHREADS) void saconv_kernel(
    const float* __restrict__ x,
    const float* __restrict__ r,
    const float* __restrict__ Wq,
    const float* __restrict__ Wk,
    const float* __restrict__ Wv,
    const float* __restrict__ Wr,
    const float* __restrict__ up,
    const float* __restrict__ vp,
    float* __restrict__ out)
{
    __shared__ float xs[TILE_H][TILE_W];   // 5.1 KB

    const int tid   = threadIdx.x;
    const int bid   = blockIdx.x;          // ((b*64 + g)*4 + chunk)
    const int chunk = bid & 3;
    const int g     = (bid >> 2) & 63;
    const int b     = bid >> 8;
    const int y0    = chunk * CHROWS;

    // per-group scalars (uniform -> s_load)
    const float wq = Wq[g];
    const float wk = Wk[g];
    const float wv = Wv[g];
    const float ug = up[g];
    const float vg = vp[g];

    // --- ro table into wave-uniform scalars (no LDS, no per-px reads) ---
    // lane k computes ro[k] = sum_c r[(g*4+c), k] * Wr[g*4+c]; then 49
    // v_readlane's give every wave the full table in SGPRs.
    const int lane = tid & 63;
    float rv = 0.f;
    if (lane < KW * KW) {
#pragma unroll
        for (int c = 0; c < 4; ++c)
            rv += r[(g * 4 + c) * (KW * KW) + lane] * Wr[g * 4 + c];
    }
    float ros[KW * KW];
#pragma unroll
    for (int k = 0; k < KW * KW; ++k)
        ros[k] = __builtin_bit_cast(float,
                   __builtin_amdgcn_readlane(__builtin_bit_cast(int, rv), k));

    // --- stage padded tile: padded rows y0-3..y0+16, cols -3..60 ---
    const float* xb = x + (size_t)(b * 64 + g) * (HW * HW);
    for (int idx = tid; idx < TILE_H * TILE_W; idx += NTHREADS) {
        const int ty = idx >> 6;
        const int tx = idx & 63;
        const int gy = y0 - PADW + ty;
        const int gx = tx - PADW;
        float v = 0.f;
        if (gy >= 0 && gy < HW && gx >= 0 && gx < HW)
            v = xb[gy * HW + gx];
        xs[ty][tx] = v;
    }
    __syncthreads();

    const int rg  = tid >> 6;                    // 0..6 row-group
    const int col = lane < HW ? lane : HW - 1;   // clamp (lanes 56-63 duplicate, store masked)
    const int lr0 = PPT * rg;                    // LDS row base for this pair

    // per-pixel constants; exp->exp2 with log2e folded in
    float a2[PPT], cc2[PPT], se[PPT], sx[PPT];
#pragma unroll
    for (int p = 0; p < PPT; ++p) {
        const float xc = xs[lr0 + p + PADW][col + PADW];
        const float q  = xc * wq;
        a2[p]  = (q + ug) * wk * LOG2E;
        cc2[p] = (q + vg) * LOG2E;
        se[p] = 0.f; sx[p] = 0.f;
    }

    // 8 shared window rows for the 2 pixels; each row slice read once.
    // Padding taps stay in softmax (xv=0, bias term remains) per reference.
#pragma unroll
    for (int R = 0; R < PPT + KW - 1; ++R) {     // 8
        float xr[KW];
#pragma unroll
        for (int j = 0; j < KW; ++j)
            xr[j] = xs[lr0 + R][col + j];
#pragma unroll
        for (int p = 0; p < PPT; ++p) {
            const int i = R - p;                 // compile-time tap row
            if (i >= 0 && i < KW) {
#pragma unroll
                for (int j = 0; j < KW; ++j) {
                    const float l2 = __builtin_fmaf(a2[p], xr[j],
                                                    cc2[p] * ros[i * KW + j]);
                    const float e  = __builtin_amdgcn_exp2f(l2);
                    se[p] += e;
                    sx[p] = __builtin_fmaf(e, xr[j], sx[p]);
                }
            }
        }
    }

    if (lane < HW) {
        const size_t base = (size_t)(b * 64 + g) * (HW * HW);
#pragma unroll
        for (int p = 0; p < PPT; ++p)
            out[base + (size_t)(y0 + lr0 + p) * HW + col] =
                wv * sx[p] * __builtin_amdgcn_rcpf(se[p]);
    }
}

extern "C" void kernel_launch(void* const* d_in, const int* in_sizes, int n_in,
                              void* d_out, int out_size, void* d_ws, size_t ws_size,
                              hipStream_t stream) {
    const float* x  = (const float*)d_in[0];
    const float* r  = (const float*)d_in[1];
    const float* Wq = (const float*)d_in[2];
    const float* Wk = (const float*)d_in[3];
    const float* Wv = (const float*)d_in[4];
    const float* Wr = (const float*)d_in[5];
    const float* up = (const float*)d_in[6];
    const float* vp = (const float*)d_in[7];
    float* out = (float*)d_out;

    const int grid = 4 * 64 * NCHUNK;  // 1024 blocks = 4 blocks/CU
    saconv_kernel<<<grid, NTHREADS, 0, stream>>>(x, r, Wq, Wk, Wv, Wr, up, vp, out);
}

// Round 8
// 79.474 us; speedup vs baseline: 1.6045x; 1.0112x over previous
//
#include <hip/hip_runtime.h>

#define KW    7
#define PADW  3
#define HW    56
#define ROWS  8
#define TILE_H (ROWS + KW - 1)   // 14
#define TILE_W 64                // 62 used, padded stride
#define NTHREADS 448             // 8 rows * 56 cols = 7 waves, all lanes productive
#define NCHUNK 7                 // 56 / ROWS

#define LOG2E 1.44269504088896340736f

__global__ __launch_bounds__(NTHREADS) void saconv_kernel(
    const float* __restrict__ x,
    const float* __restrict__ r,
    const float* __restrict__ Wq,
    const float* __restrict__ Wk,
    const float* __restrict__ Wv,
    const float* __restrict__ Wr,
    const float* __restrict__ up,
    const float* __restrict__ vp,
    float* __restrict__ out)
{
    __shared__ float xs[TILE_H][TILE_W];   // 3.5 KB only

    const int tid   = threadIdx.x;
    const int bid   = blockIdx.x;
    const int chunk = bid % NCHUNK;
    const int g     = (bid / NCHUNK) & 63;
    const int b     = bid / (NCHUNK * 64);
    const int y0    = chunk * ROWS;

    // per-group scalars (uniform -> s_load)
    const float wq = Wq[g];
    const float wk = Wk[g];
    const float wv = Wv[g];
    const float ug = up[g];
    const float vg = vp[g];

    // --- ro table into wave-uniform SGPRs (removes 49 LDS reads/px) ---
    // lane k computes ro[k] = sum_c r[(g*4+c), k] * Wr[g*4+c]; 49 readlanes
    // broadcast the table. All indices compile-time -> stays scalar.
    const int lane = tid & 63;
    float rv = 0.f;
    if (lane < KW * KW) {
#pragma unroll
        for (int c = 0; c < 4; ++c)
            rv += r[(g * 4 + c) * (KW * KW) + lane] * Wr[g * 4 + c];
    }
    float ros[KW * KW];
#pragma unroll
    for (int k = 0; k < KW * KW; ++k)
        ros[k] = __builtin_bit_cast(float,
                   __builtin_amdgcn_readlane(__builtin_bit_cast(int, rv), k));

    // --- stage padded tile: rows [y0-3, y0+10], cols [-3, 58], zeros outside ---
    const float* xb = x + (size_t)(b * 64 + g) * (HW * HW);
    for (int idx = tid; idx < TILE_H * 62; idx += NTHREADS) {
        const int ty = idx / 62;
        const int tx = idx - ty * 62;
        const int gy = y0 - PADW + ty;
        const int gx = tx - PADW;
        float v = 0.f;
        if (gy >= 0 && gy < HW && gx >= 0 && gx < HW)
            v = xb[gy * HW + gx];
        xs[ty][tx] = v;
    }
    __syncthreads();

    const int row = tid / HW;        // 0..7
    const int col = tid - row * HW;  // 0..55

    // exp -> exp2, log2e folded into per-thread constants
    const float xc  = xs[row + PADW][col + PADW];
    const float q   = xc * wq;
    const float a2  = (q + ug) * wk * LOG2E;
    const float cc2 = (q + vg) * LOG2E;

    // softmax over 49 taps; padding taps stay in the softmax (xv=0, bias
    // term remains) exactly as the reference. Per tap: 1 LDS read, 1 mul
    // (SGPR operand), 2 fma, 1 add, 1 v_exp_f32.
    float se = 0.f, sx = 0.f;
#pragma unroll
    for (int i = 0; i < KW; ++i) {
#pragma unroll
        for (int j = 0; j < KW; ++j) {
            const float xv = xs[row + i][col + j];
            const float l2 = __builtin_fmaf(a2, xv, cc2 * ros[i * KW + j]);
            const float e  = __builtin_amdgcn_exp2f(l2);
            se += e;
            sx = __builtin_fmaf(e, xv, sx);
        }
    }

    out[((size_t)(b * 64 + g) * HW + (y0 + row)) * HW + col] =
        wv * sx * __builtin_amdgcn_rcpf(se);
}

extern "C" void kernel_launch(void* const* d_in, const int* in_sizes, int n_in,
                              void* d_out, int out_size, void* d_ws, size_t ws_size,
                              hipStream_t stream) {
    const float* x  = (const float*)d_in[0];
    const float* r  = (const float*)d_in[1];
    const float* Wq = (const float*)d_in[2];
    const float* Wk = (const float*)d_in[3];
    const float* Wv = (const float*)d_in[4];
    const float* Wr = (const float*)d_in[5];
    const float* up = (const float*)d_in[6];
    const float* vp = (const float*)d_in[7];
    float* out = (float*)d_out;

    const int grid = 4 * 64 * NCHUNK;  // 1792 blocks, 49 waves/CU
    saconv_kernel<<<grid, NTHREADS, 0, stream>>>(x, r, Wq, Wk, Wv, Wr, up, vp, out);
}

// Round 9
// 75.605 us; speedup vs baseline: 1.6866x; 1.0512x over previous
//
#include <hip/hip_runtime.h>
#include <hip/hip_bf16.h>

#define KW    7
#define PADW  3
#define HW    56
#define ROWS  8
#define TILE_H (ROWS + KW - 1)   // 14
#define TILE_W 64                // 62 used, padded stride
#define NTHREADS 448             // 8 rows * 56 cols = 7 waves
#define NCHUNK 7                 // 56 / ROWS

#define LOG2E 1.44269504088896340736f

// Best measured configuration (R4: 77.26 us, reproduced by R5 at 77.27).
// Perturbations all regressed: PPT=7 (R6, occupancy cliff), PPT=2 w/ 56-lane
// waves (R7, +3us), readlane ro table (R8, +2.2us register pressure).
// Kernel slice ~11.3us of total; remaining ~66us is harness re-poison floor.
__global__ __launch_bounds__(NTHREADS) void saconv_kernel(
    const float* __restrict__ x,
    const float* __restrict__ r,
    const float* __restrict__ Wq,
    const float* __restrict__ Wk,
    const float* __restrict__ Wv,
    const float* __restrict__ Wr,
    const float* __restrict__ up,
    const float* __restrict__ vp,
    float* __restrict__ out)
{
    __shared__ float xs[TILE_H][TILE_W];
    __shared__ float ro[KW * KW];

    const int tid   = threadIdx.x;
    const int bid   = blockIdx.x;
    const int chunk = bid % NCHUNK;
    const int g     = (bid / NCHUNK) & 63;
    const int b     = bid / (NCHUNK * 64);
    const int y0    = chunk * ROWS;

    // per-group scalars (uniform -> scalar loads)
    const float wq = Wq[g];
    const float wk = Wk[g];
    const float wv = Wv[g];
    const float ug = up[g];
    const float vg = vp[g];

    // r_o[g][pos] = sum_c r[(g*4+c), pos] * Wr[g*4+c]  (pos = i*7+j row-major,
    // matching _windows' (i,j) flatten order)
    if (tid < KW * KW) {
        float acc = 0.f;
#pragma unroll
        for (int c = 0; c < 4; ++c) {
            acc += r[(g * 4 + c) * (KW * KW) + tid] * Wr[g * 4 + c];
        }
        ro[tid] = acc;
    }

    // stage padded tile: global rows [y0-3, y0+10], cols [-3, 58], zeros outside
    const float* xb = x + (size_t)(b * 64 + g) * (HW * HW);
    for (int idx = tid; idx < TILE_H * 62; idx += NTHREADS) {
        const int ty = idx / 62;
        const int tx = idx - ty * 62;
        const int gy = y0 - PADW + ty;
        const int gx = tx - PADW;
        float v = 0.f;
        if (gy >= 0 && gy < HW && gx >= 0 && gx < HW)
            v = xb[gy * HW + gx];
        xs[ty][tx] = v;
    }
    __syncthreads();

    const int row = tid / HW;        // 0..7
    const int col = tid - row * HW;  // 0..55

    // exp(l) = exp2(l*log2e): fold log2e into the per-thread constants so the
    // inner loop is fma + v_exp_f32 + add + fma per tap (no extra mul).
    const float xc  = xs[row + PADW][col + PADW];
    const float q   = xc * wq;
    const float a2  = (q + ug) * wk * LOG2E;
    const float cc2 = (q + vg) * LOG2E;

    // softmax over 49 taps, no max-subtraction (|logit| << 126 in exp2 domain).
    // Padding taps stay in the softmax: xv=0 there, logit = cc*ro[pos] (matches ref).
    float se = 0.f, sx = 0.f;
#pragma unroll
    for (int i = 0; i < KW; ++i) {
#pragma unroll
        for (int j = 0; j < KW; ++j) {
            const float xv = xs[row + i][col + j];
            const float l2 = __builtin_fmaf(a2, xv, cc2 * ro[i * KW + j]);
            const float e  = __builtin_amdgcn_exp2f(l2);   // bare v_exp_f32
            se += e;
            sx = __builtin_fmaf(e, xv, sx);
        }
    }

    // v_rcp_f32 (~1 ulp) instead of the precise-division sequence.
    out[((size_t)(b * 64 + g) * HW + (y0 + row)) * HW + col] =
        wv * sx * __builtin_amdgcn_rcpf(se);
}

extern "C" void kernel_launch(void* const* d_in, const int* in_sizes, int n_in,
                              void* d_out, int out_size, void* d_ws, size_t ws_size,
                              hipStream_t stream) {
    const float* x  = (const float*)d_in[0];
    const float* r  = (const float*)d_in[1];
    const float* Wq = (const float*)d_in[2];
    const float* Wk = (const float*)d_in[3];
    const float* Wv = (const float*)d_in[4];
    const float* Wr = (const float*)d_in[5];
    const float* up = (const float*)d_in[6];
    const float* vp = (const float*)d_in[7];
    float* out = (float*)d_out;

    const int grid = 4 * 64 * NCHUNK;  // B * G * chunks = 1792
    saconv_kernel<<<grid, NTHREADS, 0, stream>>>(x, r, Wq, Wk, Wv, Wr, up, vp, out);
}